// Round 1
// baseline (1379.397 us; speedup 1.0000x reference)
//
#include <hip/hip_runtime.h>
#include <math.h>

#define B_ 1024
#define V_ 5000
#define N_ 10000
#define T_ 50
#define H_ 200
#define K_ 20
#define EPS_ 1e-5f

__device__ __forceinline__ float sp_(float x) {
    return (x > 20.f) ? x : log1pf(expf(x));
}

// ---------------- init: zero the accumulators ----------------
__global__ __launch_bounds__(256) void k_init(float* e1a, float* buckets, int* cnt) {
    int i = blockIdx.x * 256 + threadIdx.x;
    if (i < B_ * H_) e1a[i] = 0.f;
    if (i < 1024)    buckets[i] = 0.f;
    if (i < 64)      cnt[i] = 0;
}

// ---------------- GEMM1: e1a_raw = inputs @ W11^T  (atomic k-split) ----------------
// grid (16, 25): 64-row tile x full 200 cols, K-chunk = 200
__global__ __launch_bounds__(256) void k_gemm1(const float* __restrict__ X,
                                               const float* __restrict__ W,
                                               float* __restrict__ e1a) {
    __shared__ __align__(16) float Al[64][8];
    __shared__ __align__(16) float Bl[200][8];
    const int tid = threadIdx.x;
    const int r = tid & 31, c = tid >> 5;       // r: row pair, c: 0..7 col group of 25
    const int m0 = blockIdx.x * 64;
    const int k0 = blockIdx.y * 200;
    float acc0[25], acc1[25];
#pragma unroll
    for (int j = 0; j < 25; ++j) { acc0[j] = 0.f; acc1[j] = 0.f; }
    for (int kb = 0; kb < 200; kb += 8) {
        __syncthreads();
        if (tid < 128) {
            int row = tid >> 1, kp = (tid & 1) * 4;
            *(float4*)&Al[row][kp] = *(const float4*)&X[(size_t)(m0 + row) * V_ + k0 + kb + kp];
        }
        for (int i = tid; i < 400; i += 256) {
            int h = i >> 1, kp = (i & 1) * 4;
            *(float4*)&Bl[h][kp] = *(const float4*)&W[(size_t)h * V_ + k0 + kb + kp];
        }
        __syncthreads();
#pragma unroll
        for (int kc = 0; kc < 8; kc += 4) {
            float4 a0 = *(const float4*)&Al[r][kc];
            float4 a1 = *(const float4*)&Al[r + 32][kc];
#pragma unroll
            for (int j = 0; j < 25; ++j) {
                float4 bb = *(const float4*)&Bl[c * 25 + j][kc];
                acc0[j] += a0.x * bb.x + a0.y * bb.y + a0.z * bb.z + a0.w * bb.w;
                acc1[j] += a1.x * bb.x + a1.y * bb.y + a1.z * bb.z + a1.w * bb.w;
            }
        }
    }
#pragma unroll
    for (int j = 0; j < 25; ++j) {
        atomicAdd(&e1a[(size_t)(m0 + r) * H_ + c * 25 + j], acc0[j]);
        atomicAdd(&e1a[(size_t)(m0 + r + 32) * H_ + c * 25 + j], acc1[j]);
    }
}

// ---------------- encoder tail: softplus -> layer2 -> layer3 linear ----------------
__global__ __launch_bounds__(256) void k_enc_tail(const float* __restrict__ e1a,
                                                  const float* __restrict__ b11,
                                                  const float* __restrict__ W12,
                                                  const float* __restrict__ b12,
                                                  const float* __restrict__ W21,
                                                  const float* __restrict__ b21,
                                                  float* __restrict__ thetalin) {
    __shared__ float arow[H_];
    __shared__ float brow[H_];
    __shared__ float Wl[H_ * T_];   // 10000 floats, reused
    const int b = blockIdx.x, tid = threadIdx.x;
    if (tid < H_) arow[tid] = sp_(e1a[(size_t)b * H_ + tid] + b11[tid]);
    float acc = (tid < H_) ? b12[tid] : 0.f;
    for (int kc = 0; kc < 4; ++kc) {
        __syncthreads();
        for (int i = tid; i < H_ * T_; i += 256) {
            int h = i / T_, k = i % T_;
            Wl[i] = W12[h * H_ + kc * T_ + k];      // Wl layout [h][50]
        }
        __syncthreads();
        if (tid < H_) {
#pragma unroll 10
            for (int k = 0; k < T_; ++k) acc += arow[kc * T_ + k] * Wl[tid * T_ + k];
        }
    }
    __syncthreads();
    if (tid < H_) brow[tid] = sp_(acc);
    __syncthreads();
    for (int i = tid; i < T_ * H_; i += 256) Wl[i] = W21[i];  // [t][200]
    __syncthreads();
    if (tid < T_) {
        float a2 = b21[tid];
        for (int h = 0; h < H_; ++h) a2 += brow[h] * Wl[tid * H_ + h];
        thetalin[b * T_ + tid] = a2;
    }
}

// ---------------- BN stats over batch for theta ----------------
__global__ __launch_bounds__(64) void k_bnstats(const float* __restrict__ thetalin,
                                                const float* __restrict__ g,
                                                const float* __restrict__ be,
                                                float* scale, float* shift) {
    int t = threadIdx.x;
    if (t >= T_) return;
    double s = 0.0, s2 = 0.0;
    for (int b = 0; b < B_; ++b) {
        float x = thetalin[b * T_ + t];
        s += x; s2 += (double)x * x;
    }
    double mean = s / B_;
    float var = (float)(s2 / B_ - mean * mean);
    float sc = g[t] / sqrtf(var + EPS_);
    scale[t] = sc;
    shift[t] = be[t] - (float)mean * sc;
}

// ---------------- softmax(theta), argmax -> enc_idx, counts, quant_loss ----------------
__global__ __launch_bounds__(64) void k_st(const float* __restrict__ thetalin,
                                           const float* __restrict__ scale,
                                           const float* __restrict__ shift,
                                           float* __restrict__ st, float* __restrict__ stnorm,
                                           int* __restrict__ enc_idx, int* __restrict__ cnt,
                                           float* __restrict__ buckets) {
    const int b = blockIdx.x, t = threadIdx.x;
    float x = (t < T_) ? thetalin[b * T_ + t] * scale[t] + shift[t] : -INFINITY;
    float m = x;
#pragma unroll
    for (int off = 32; off; off >>= 1) m = fmaxf(m, __shfl_xor(m, off));
    float e = (t < T_) ? expf(x - m) : 0.f;
    float ssum = e;
#pragma unroll
    for (int off = 32; off; off >>= 1) ssum += __shfl_xor(ssum, off);
    float stv = e / ssum;
    if (t < T_) st[b * T_ + t] = stv;
    float sn = stv * stv;
#pragma unroll
    for (int off = 32; off; off >>= 1) sn += __shfl_xor(sn, off);
    // argmax of x, first index wins ties  (== argmin of VQ distance)
    float bv = x; int bi = (t < T_) ? t : (1 << 30);
#pragma unroll
    for (int off = 32; off; off >>= 1) {
        float ov = __shfl_xor(bv, off); int oi = __shfl_xor(bi, off);
        if (ov > bv || (ov == bv && oi < bi)) { bv = ov; bi = oi; }
    }
    if (t == 0) {
        enc_idx[b] = bi;
        atomicAdd(&cnt[bi], 1);
        stnorm[b] = sn;
        float stmax = 1.f / ssum;  // st at argmax
        atomicAdd(&buckets[b], (1.25f / (float)(B_ * T_)) * (sn + 1.f - 2.f * stmax));
    }
}

// ---------------- decoder BN -> A[t][v] = log-softmax numerator rows ----------------
__global__ __launch_bounds__(256) void k_amat(const float* __restrict__ Wd,
                                              const int* __restrict__ cnt,
                                              const float* __restrict__ gd,
                                              const float* __restrict__ bd,
                                              float* __restrict__ A) {
    __shared__ float cl[T_];
    const int tid = threadIdx.x;
    if (tid < T_) cl[tid] = (float)cnt[tid];
    __syncthreads();
    int v = blockIdx.x * 256 + tid;
    if (v >= V_) return;
    float mean = 0.f, ex2 = 0.f;
#pragma unroll
    for (int t = 0; t < T_; ++t) {
        float w = Wd[v * T_ + t];
        mean += cl[t] * w; ex2 += cl[t] * w * w;
    }
    mean *= (1.f / B_); ex2 *= (1.f / B_);
    float rstd = 1.f / sqrtf(ex2 - mean * mean + EPS_);
    float g = gd[v], bb = bd[v];
#pragma unroll
    for (int t = 0; t < T_; ++t)
        A[(size_t)t * V_ + v] = (Wd[v * T_ + t] - mean) * rstd * g + bb;
}

// ---------------- lse[t] = logsumexp_v A[t][v] ----------------
__global__ __launch_bounds__(256) void k_lse(const float* __restrict__ A, float* __restrict__ lse) {
    __shared__ float red[4];
    const int t = blockIdx.x, tid = threadIdx.x;
    const float* row = A + (size_t)t * V_;
    float m = -INFINITY;
    for (int i = tid; i < V_; i += 256) m = fmaxf(m, row[i]);
#pragma unroll
    for (int off = 32; off; off >>= 1) m = fmaxf(m, __shfl_xor(m, off));
    if ((tid & 63) == 0) red[tid >> 6] = m;
    __syncthreads();
    m = fmaxf(fmaxf(red[0], red[1]), fmaxf(red[2], red[3]));
    float s = 0.f;
    for (int i = tid; i < V_; i += 256) s += expf(row[i] - m);
#pragma unroll
    for (int off = 32; off; off >>= 1) s += __shfl_xor(s, off);
    __syncthreads();
    if ((tid & 63) == 0) red[tid >> 6] = s;
    __syncthreads();
    if (tid == 0) lse[t] = m + logf(red[0] + red[1] + red[2] + red[3]);
}

// ---------------- tbnorm[n] = ||theta_bank[n]||^2 ----------------
__global__ __launch_bounds__(256) void k_tbnorm(const float* __restrict__ tb, float* __restrict__ tbn) {
    int n = blockIdx.x * 256 + threadIdx.x;
    if (n >= N_) return;
    float s = 0.f;
#pragma unroll
    for (int t = 0; t < T_; ++t) { float x = tb[n * T_ + t]; s += x * x; }
    tbn[n] = s;
}

// ---------------- fused cost + fuse + per-half top-20 ----------------
// grid 512: blockIdx = (rowblk<<1)|half ; 4 rows/block, one wave per row, 5000 n per half
__global__ __launch_bounds__(256) void k_fuse_topk(const float* __restrict__ st,
                                                   const float* __restrict__ stnorm,
                                                   const float* __restrict__ tb,
                                                   const float* __restrict__ tbn,
                                                   const float* __restrict__ Mcos,
                                                   const float* __restrict__ Mcoo,
                                                   const int* __restrict__ idx,
                                                   float* __restrict__ cand_v,
                                                   int* __restrict__ cand_i) {
    __shared__ __align__(16) float tbl[256 * T_];
    const int tid = threadIdx.x;
    const int lane = tid & 63, wv = tid >> 6;
    const int half = blockIdx.x & 1;
    const int r = (blockIdx.x >> 1) * 4 + wv;
    const int n0 = half * 5000;
    float sreg[T_];
#pragma unroll
    for (int k = 0; k < T_; ++k) sreg[k] = st[r * T_ + k];
    const float snr = stnorm[r];
    const int myidx = idx[r];
    const float* mcr = Mcos + (size_t)myidx * N_;
    const float* mor = Mcoo + (size_t)myidx * N_;
    float tv[K_]; int ti[K_];
#pragma unroll
    for (int s = 0; s < K_; ++s) { tv[s] = INFINITY; ti[s] = -1; }
    float worst = INFINITY;
    for (int c0 = 0; c0 < 5000; c0 += 256) {
        int nrows = min(256, 5000 - c0);
        __syncthreads();
        {
            const float4* src = (const float4*)(tb + (size_t)(n0 + c0) * T_);
            float4* dst = (float4*)tbl;
            int cnt4 = nrows * T_ / 4;
            for (int i = tid; i < cnt4; i += 256) dst[i] = src[i];
        }
        __syncthreads();
#pragma unroll
        for (int jj = 0; jj < 4; ++jj) {
            int nn = lane + 64 * jj;
            int n = n0 + c0 + nn;
            if (nn < nrows && n != myidx) {
                const float2* t2 = (const float2*)(tbl + nn * T_);
                float d = 0.f;
#pragma unroll
                for (int k = 0; k < T_ / 2; ++k) {
                    float2 w = t2[k];
                    d += sreg[2 * k] * w.x + sreg[2 * k + 1] * w.y;
                }
                float cost = snr + tbn[n] - 2.f * d;
                float f = 0.5f * cost * cost + 0.5f * (0.5f * mcr[n] + 0.5f * mor[n]);
                if (f < worst) {
                    bool done = false;
#pragma unroll
                    for (int s = 0; s < K_; ++s) {
                        bool mm = (!done) && (tv[s] == worst);
                        if (mm) { tv[s] = f; ti[s] = n; done = true; }
                    }
                    worst = tv[0];
#pragma unroll
                    for (int s = 1; s < K_; ++s) worst = fmaxf(worst, tv[s]);
                }
            }
        }
    }
    // wave-level merge: extract the 20 smallest across the 64 lane lists
    for (int it = 0; it < K_; ++it) {
        float mv = INFINITY; int mi = -1, ms = -1;
#pragma unroll
        for (int s = 0; s < K_; ++s) {
            bool better = tv[s] < mv;
            mv = better ? tv[s] : mv;
            mi = better ? ti[s] : mi;
            ms = better ? s : ms;
        }
        float bv = mv; int bn = mi, bl = lane, bs = ms;
#pragma unroll
        for (int off = 32; off; off >>= 1) {
            float ov = __shfl_xor(bv, off); int on = __shfl_xor(bn, off);
            int ol = __shfl_xor(bl, off);   int os = __shfl_xor(bs, off);
            if (ov < bv || (ov == bv && on < bn)) { bv = ov; bn = on; bl = ol; bs = os; }
        }
        if (lane == 0) {
            cand_v[(r * 2 + half) * K_ + it] = bv;
            cand_i[(r * 2 + half) * K_ + it] = bn;
        }
        if (lane == bl) {
#pragma unroll
            for (int s = 0; s < K_; ++s)
                if (s == bs) tv[s] = INFINITY;
        }
    }
}

// ---------------- merge the two per-half top-20 lists into final top-20 ----------------
__global__ __launch_bounds__(64) void k_merge40(const float* __restrict__ cand_v,
                                                const int* __restrict__ cand_i,
                                                int* __restrict__ topk) {
    const int b = blockIdx.x, lane = threadIdx.x;
    float v = (lane < 2 * K_) ? cand_v[b * 2 * K_ + lane] : INFINITY;
    int id = (lane < 2 * K_) ? cand_i[b * 2 * K_ + lane] : -1;
    for (int it = 0; it < K_; ++it) {
        float bv = v; int bn = id, bl = lane;
#pragma unroll
        for (int off = 32; off; off >>= 1) {
            float ov = __shfl_xor(bv, off); int on = __shfl_xor(bn, off);
            int ol = __shfl_xor(bl, off);
            if (ov < bv || (ov == bv && on < bn)) { bv = ov; bn = on; bl = ol; }
        }
        if (lane == 0) topk[b * K_ + it] = bn;
        if (lane == bl) v = INFINITY;
    }
}

// ---------------- aug part of rec_loss: per (b,k) row dot + row sum ----------------
__global__ __launch_bounds__(256) void k_aug(const float* __restrict__ td,
                                             const float* __restrict__ A,
                                             const float* __restrict__ lse,
                                             const int* __restrict__ topk,
                                             const int* __restrict__ enc_idx,
                                             const int* __restrict__ flag,
                                             float* __restrict__ buckets) {
    __shared__ float red[8];
    const int tid = threadIdx.x;
    const int b = blockIdx.x / K_;
    const int k = blockIdx.x % K_;
    const int j = topk[b * K_ + k];
    const int t = enc_idx[b];
    const float4* trow = (const float4*)(td + (size_t)j * V_);
    const float4* arow = (const float4*)(A + (size_t)t * V_);
    float dot = 0.f, s = 0.f;
    for (int i = tid; i < V_ / 4; i += 256) {
        float4 a = trow[i]; float4 w = arow[i];
        dot += a.x * w.x + a.y * w.y + a.z * w.z + a.w * w.w;
        s += a.x + a.y + a.z + a.w;
    }
#pragma unroll
    for (int off = 32; off; off >>= 1) {
        dot += __shfl_xor(dot, off);
        s += __shfl_xor(s, off);
    }
    if ((tid & 63) == 0) { red[(tid >> 6) * 2] = dot; red[(tid >> 6) * 2 + 1] = s; }
    __syncthreads();
    if (tid == 0 && *flag != 0) {
        float D = red[0] + red[2] + red[4] + red[6];
        float S = red[1] + red[3] + red[5] + red[7];
        atomicAdd(&buckets[blockIdx.x & 1023], (lse[t] * S - D) * (1.f / ((float)B_ * (float)K_)));
    }
}

// ---------------- inputs part of rec_loss ----------------
__global__ __launch_bounds__(256) void k_xin(const float* __restrict__ inputs,
                                             const float* __restrict__ A,
                                             const float* __restrict__ lse,
                                             const int* __restrict__ enc_idx,
                                             float* __restrict__ buckets) {
    __shared__ float red[8];
    const int tid = threadIdx.x, b = blockIdx.x;
    const int t = enc_idx[b];
    const float4* xr = (const float4*)(inputs + (size_t)b * V_);
    const float4* ar = (const float4*)(A + (size_t)t * V_);
    float dot = 0.f, s = 0.f;
    for (int i = tid; i < V_ / 4; i += 256) {
        float4 a = xr[i]; float4 w = ar[i];
        dot += a.x * w.x + a.y * w.y + a.z * w.z + a.w * w.w;
        s += a.x + a.y + a.z + a.w;
    }
#pragma unroll
    for (int off = 32; off; off >>= 1) {
        dot += __shfl_xor(dot, off);
        s += __shfl_xor(s, off);
    }
    if ((tid & 63) == 0) { red[(tid >> 6) * 2] = dot; red[(tid >> 6) * 2 + 1] = s; }
    __syncthreads();
    if (tid == 0) {
        float D = red[0] + red[2] + red[4] + red[6];
        float S = red[1] + red[3] + red[5] + red[7];
        atomicAdd(&buckets[b], (lse[t] * S - D) * (1.f / (float)B_));
    }
}

// ---------------- final reduce ----------------
__global__ __launch_bounds__(256) void k_final(const float* __restrict__ buckets, float* __restrict__ out) {
    __shared__ float red[4];
    const int tid = threadIdx.x;
    float v = buckets[tid] + buckets[tid + 256] + buckets[tid + 512] + buckets[tid + 768];
#pragma unroll
    for (int off = 32; off; off >>= 1) v += __shfl_xor(v, off);
    if ((tid & 63) == 0) red[tid >> 6] = v;
    __syncthreads();
    if (tid == 0) out[0] = red[0] + red[1] + red[2] + red[3];
}

extern "C" void kernel_launch(void* const* d_in, const int* in_sizes, int n_in,
                              void* d_out, int out_size, void* d_ws, size_t ws_size,
                              hipStream_t stream) {
    const int*   idx    = (const int*)d_in[0];
    const float* inputs = (const float*)d_in[1];
    const int*   flag   = (const int*)d_in[2];
    const float* td     = (const float*)d_in[3];
    const float* Mcos   = (const float*)d_in[4];
    const float* Mcoo   = (const float*)d_in[5];
    const float* tb     = (const float*)d_in[6];
    const float* W11    = (const float*)d_in[7];
    const float* b11    = (const float*)d_in[8];
    const float* W12    = (const float*)d_in[9];
    const float* b12    = (const float*)d_in[10];
    const float* W21    = (const float*)d_in[11];
    const float* b21    = (const float*)d_in[12];
    const float* gm     = (const float*)d_in[13];
    const float* bm     = (const float*)d_in[14];
    const float* gd     = (const float*)d_in[15];
    const float* bd     = (const float*)d_in[16];
    const float* Wd     = (const float*)d_in[17];
    float* out = (float*)d_out;

    float* ws       = (float*)d_ws;
    float* e1a      = ws;                   // 204800
    float* thetalin = e1a + 204800;         // 51200
    float* st       = thetalin + 51200;     // 51200
    float* stnorm   = st + 51200;           // 1024
    float* scale    = stnorm + 1024;        // 64
    float* shift    = scale + 64;           // 64
    float* Amat     = shift + 64;           // 250000
    float* lse      = Amat + 250000;        // 64
    float* tbn      = lse + 64;             // 10000
    float* buckets  = tbn + 10000;          // 1024
    float* cand_v   = buckets + 1024;       // 40960
    int*   enc_idx  = (int*)(cand_v + 40960); // 1024
    int*   cnt      = enc_idx + 1024;       // 64
    int*   cand_i   = cnt + 64;             // 40960
    int*   topk     = cand_i + 40960;       // 20480

    k_init<<<800, 256, 0, stream>>>(e1a, buckets, cnt);
    k_gemm1<<<dim3(16, 25), 256, 0, stream>>>(inputs, W11, e1a);
    k_enc_tail<<<1024, 256, 0, stream>>>(e1a, b11, W12, b12, W21, b21, thetalin);
    k_bnstats<<<1, 64, 0, stream>>>(thetalin, gm, bm, scale, shift);
    k_st<<<1024, 64, 0, stream>>>(thetalin, scale, shift, st, stnorm, enc_idx, cnt, buckets);
    k_amat<<<20, 256, 0, stream>>>(Wd, cnt, gd, bd, Amat);
    k_lse<<<50, 256, 0, stream>>>(Amat, lse);
    k_tbnorm<<<40, 256, 0, stream>>>(tb, tbn);
    k_fuse_topk<<<512, 256, 0, stream>>>(st, stnorm, tb, tbn, Mcos, Mcoo, idx, cand_v, cand_i);
    k_merge40<<<1024, 64, 0, stream>>>(cand_v, cand_i, topk);
    k_aug<<<20480, 256, 0, stream>>>(td, Amat, lse, topk, enc_idx, flag, buckets);
    k_xin<<<1024, 256, 0, stream>>>(inputs, Amat, lse, enc_idx, buckets);
    k_final<<<1, 256, 0, stream>>>(buckets, out);
}